// Round 1
// baseline (869.347 us; speedup 1.0000x reference)
//
#include <hip/hip_runtime.h>
#include <math.h>

#define NNODES 50000
#define NEG_SLOPE 0.2f

// ---------------------------------------------------------------------------
// CSR build
// ---------------------------------------------------------------------------
__global__ void init_deg(int* deg, int N) {
    int i = blockIdx.x * 256 + threadIdx.x;
    if (i < N) deg[i] = 1;  // self-loop
}

__global__ void count_deg(const int* __restrict__ ei, int E, int* deg) {
    int e = blockIdx.x * 256 + threadIdx.x;
    if (e < E) atomicAdd(&deg[ei[E + e]], 1);  // row 1 = dst
}

// single-block exclusive scan of deg[N] -> off[N+1], cursor[N]
__global__ __launch_bounds__(1024) void scan_deg(const int* __restrict__ deg,
                                                 int* off, int* cursor, int N) {
    __shared__ int sdata[1024];
    int t = threadIdx.x;
    int chunk = (N + 1023) >> 10;
    int base = t * chunk;
    int lim = min(base + chunk, N);
    int s = 0;
    for (int i = base; i < lim; ++i) s += deg[i];
    sdata[t] = s;
    __syncthreads();
    for (int o = 1; o < 1024; o <<= 1) {
        int v = (t >= o) ? sdata[t - o] : 0;
        __syncthreads();
        sdata[t] += v;
        __syncthreads();
    }
    int run = sdata[t] - s;  // exclusive
    for (int i = base; i < lim; ++i) {
        off[i] = run; cursor[i] = run; run += deg[i];
    }
    if (t == 1023) off[N] = sdata[1023];
}

__global__ void scatter_edges(const int* __restrict__ ei, int E, int N,
                              int* cursor, int* __restrict__ slot) {
    int e = blockIdx.x * 256 + threadIdx.x;
    if (e >= E + N) return;
    int s, d;
    if (e < E) { s = ei[e]; d = ei[E + e]; }
    else       { s = e - E; d = e - E; }       // self-loops
    int pos = atomicAdd(&cursor[d], 1);
    slot[pos] = s;
}

// ---------------------------------------------------------------------------
// GEMM1: H1[M,64] = X[M,512] @ W1[512,64]   (f32, tiled 64x64, 4x4 microtile)
// ---------------------------------------------------------------------------
__global__ __launch_bounds__(256) void gemm1(const float* __restrict__ X,
                                             const float* __restrict__ W,
                                             float* __restrict__ H, int M) {
    __shared__ float As[32][64];  // [k][m]
    __shared__ float Bs[32][64];  // [k][n]
    int tid = threadIdx.x;
    int m0 = blockIdx.x * 64;
    int tc = tid & 15;   // col group (n = tc*4..+3)
    int tr = tid >> 4;   // row group (m = tr*4..+3)
    float acc[4][4] = {};
    for (int k0 = 0; k0 < 512; k0 += 32) {
        // load A tile (transpose into [k][m])
        int kb = (tid & 7) * 4;
        int r = tid >> 3;  // 0..31
        for (int rr = r; rr < 64; rr += 32) {
            int gm = m0 + rr;
            float4 v = make_float4(0.f, 0.f, 0.f, 0.f);
            if (gm < M) v = *(const float4*)(X + (size_t)gm * 512 + k0 + kb);
            As[kb + 0][rr] = v.x; As[kb + 1][rr] = v.y;
            As[kb + 2][rr] = v.z; As[kb + 3][rr] = v.w;
        }
        // load B tile
        int n4 = (tid & 15) * 4;
        int kk = tid >> 4;  // 0..15
        for (int k2 = kk; k2 < 32; k2 += 16) {
            float4 v = *(const float4*)(W + (size_t)(k0 + k2) * 64 + n4);
            *(float4*)&Bs[k2][n4] = v;
        }
        __syncthreads();
#pragma unroll
        for (int k = 0; k < 32; ++k) {
            float4 a4 = *(const float4*)&As[k][tr * 4];
            float4 b4 = *(const float4*)&Bs[k][tc * 4];
            float a[4] = {a4.x, a4.y, a4.z, a4.w};
            float b[4] = {b4.x, b4.y, b4.z, b4.w};
#pragma unroll
            for (int i = 0; i < 4; ++i)
#pragma unroll
                for (int j = 0; j < 4; ++j) acc[i][j] += a[i] * b[j];
        }
        __syncthreads();
    }
#pragma unroll
    for (int i = 0; i < 4; ++i) {
        int gm = m0 + tr * 4 + i;
        if (gm < M)
            *(float4*)(H + (size_t)gm * 64 + tc * 4) =
                make_float4(acc[i][0], acc[i][1], acc[i][2], acc[i][3]);
    }
}

// ---------------------------------------------------------------------------
// att1: a_src1[n,h], a_dst1[n,h] from H1[n, h*8+c]
// ---------------------------------------------------------------------------
__global__ void att1_kernel(const float* __restrict__ H1,
                            const float* __restrict__ att_src,
                            const float* __restrict__ att_dst,
                            float* __restrict__ a_src, float* __restrict__ a_dst,
                            int N) {
    int idx = blockIdx.x * 256 + threadIdx.x;  // idx = n*8 + h
    if (idx >= N * 8) return;
    int h = idx & 7;
    const float* hp = H1 + (size_t)idx * 8;
    float4 h0 = *(const float4*)hp;
    float4 h1v = *(const float4*)(hp + 4);
    const float* sp = att_src + h * 8;
    const float* dp = att_dst + h * 8;
    float4 s0 = *(const float4*)sp, s1 = *(const float4*)(sp + 4);
    float4 d0 = *(const float4*)dp, d1 = *(const float4*)(dp + 4);
    float as = h0.x * s0.x + h0.y * s0.y + h0.z * s0.z + h0.w * s0.w +
               h1v.x * s1.x + h1v.y * s1.y + h1v.z * s1.z + h1v.w * s1.w;
    float ad = h0.x * d0.x + h0.y * d0.y + h0.z * d0.z + h0.w * d0.w +
               h1v.x * d1.x + h1v.y * d1.y + h1v.z * d1.z + h1v.w * d1.w;
    a_src[idx] = as;
    a_dst[idx] = ad;
}

// ---------------------------------------------------------------------------
// agg1: wave per dst node. lane = h*8+c. Softmax over in-edges (no max pass:
// |e| <= ~4 so exp is safe; softmax is shift-invariant). Then +b1, ReLU.
// ---------------------------------------------------------------------------
__global__ __launch_bounds__(256) void agg1(const int* __restrict__ off,
                                            const int* __restrict__ slot,
                                            const float* __restrict__ H1,
                                            const float* __restrict__ a_src,
                                            const float* __restrict__ a_dst,
                                            const float* __restrict__ b1,
                                            float* __restrict__ H1R) {
    int wid = threadIdx.x >> 6, lane = threadIdx.x & 63;
    int d = blockIdx.x * 4 + wid;  // grid exact: 12500*4 = 50000
    int h = lane >> 3;
    int beg = off[d], end = off[d + 1];
    float adst = a_dst[(size_t)d * 8 + h];
    // pass 1: denom, 8 edges/iter (sub-lane = lane&7), reduce within head group
    float part = 0.f;
    for (int i = beg + (lane & 7); i < end; i += 8) {
        int s = slot[i];
        float e = a_src[(size_t)s * 8 + h] + adst;
        e = (e >= 0.f) ? e : NEG_SLOPE * e;
        part += __expf(e);
    }
    part += __shfl_xor(part, 1);
    part += __shfl_xor(part, 2);
    part += __shfl_xor(part, 4);
    float inv = 1.f / (part + 1e-16f);
    // pass 2: weighted gather
    float acc = 0.f;
    for (int i = beg; i < end; ++i) {
        int s = slot[i];
        float e = a_src[(size_t)s * 8 + h] + adst;
        e = (e >= 0.f) ? e : NEG_SLOPE * e;
        acc += __expf(e) * inv * H1[(size_t)s * 64 + lane];
    }
    float v = acc + b1[lane];
    H1R[(size_t)d * 64 + lane] = (v > 0.f) ? v : 0.f;
}

// ---------------------------------------------------------------------------
// GEMM2 + att2 fused: wave per node. H2[n,40] = H1R[n,:] @ W2[64,40];
// a_src2[n] = H2[n,:].att_src2 ; a_dst2[n] = H2[n,:].att_dst2
// ---------------------------------------------------------------------------
__global__ __launch_bounds__(256) void gemm2_att2(const float* __restrict__ H1R,
                                                  const float* __restrict__ W2,
                                                  const float* __restrict__ att_src2,
                                                  const float* __restrict__ att_dst2,
                                                  float* __restrict__ H2,
                                                  float* __restrict__ a_src2,
                                                  float* __restrict__ a_dst2) {
    __shared__ float W2s[64 * 40];
    __shared__ float rows[4][64];
    int tid = threadIdx.x;
    int wid = tid >> 6, lane = tid & 63;
    for (int i = tid; i < 64 * 40; i += 256) W2s[i] = W2[i];
    int node = blockIdx.x * 4 + wid;  // grid exact
    rows[wid][lane] = H1R[(size_t)node * 64 + lane];
    __syncthreads();
    int c = lane;
    int cc = (c < 40) ? c : 0;
    float acc = 0.f;
#pragma unroll 8
    for (int k = 0; k < 64; ++k) acc += rows[wid][k] * W2s[k * 40 + cc];
    if (c < 40) H2[(size_t)node * 40 + c] = acc;
    float ps = (c < 40) ? acc * att_src2[c] : 0.f;
    float pd = (c < 40) ? acc * att_dst2[c] : 0.f;
#pragma unroll
    for (int m = 32; m >= 1; m >>= 1) {
        ps += __shfl_xor(ps, m);
        pd += __shfl_xor(pd, m);
    }
    if (lane == 0) { a_src2[node] = ps; a_dst2[node] = pd; }
}

// ---------------------------------------------------------------------------
// agg2 + bias + log_softmax: wave per dst node, lane = channel (40 active)
// ---------------------------------------------------------------------------
__global__ __launch_bounds__(256) void agg2(const int* __restrict__ off,
                                            const int* __restrict__ slot,
                                            const float* __restrict__ H2,
                                            const float* __restrict__ a_src2,
                                            const float* __restrict__ a_dst2,
                                            const float* __restrict__ b2,
                                            float* __restrict__ out) {
    int wid = threadIdx.x >> 6, lane = threadIdx.x & 63;
    int d = blockIdx.x * 4 + wid;  // grid exact
    int beg = off[d], end = off[d + 1];
    float adst = a_dst2[d];
    // pass 1: denom, parallel over lanes
    float part = 0.f;
    for (int i = beg + lane; i < end; i += 64) {
        int s = slot[i];
        float e = a_src2[s] + adst;
        e = (e >= 0.f) ? e : NEG_SLOPE * e;
        part += __expf(e);
    }
#pragma unroll
    for (int m = 32; m >= 1; m >>= 1) part += __shfl_xor(part, m);
    float inv = 1.f / (part + 1e-16f);
    int c = lane;
    int cc = (c < 40) ? c : 0;
    // pass 2: weighted gather
    float acc = 0.f;
    for (int i = beg; i < end; ++i) {
        int s = slot[i];
        float e = a_src2[s] + adst;
        e = (e >= 0.f) ? e : NEG_SLOPE * e;
        acc += __expf(e) * inv * H2[(size_t)s * 40 + cc];
    }
    float v = acc + b2[cc];
    // log_softmax over 40 channels
    float vm = (c < 40) ? v : -3.0e38f;
#pragma unroll
    for (int m = 32; m >= 1; m >>= 1) vm = fmaxf(vm, __shfl_xor(vm, m));
    float se = (c < 40) ? __expf(v - vm) : 0.f;
#pragma unroll
    for (int m = 32; m >= 1; m >>= 1) se += __shfl_xor(se, m);
    float res = v - vm - __logf(se);
    if (c < 40) out[(size_t)d * 40 + c] = res;
}

// ---------------------------------------------------------------------------
extern "C" void kernel_launch(void* const* d_in, const int* in_sizes, int n_in,
                              void* d_out, int out_size, void* d_ws, size_t ws_size,
                              hipStream_t stream) {
    const float* x   = (const float*)d_in[0];
    const int*   ei  = (const int*)d_in[1];
    const float* W1  = (const float*)d_in[2];
    const float* as1 = (const float*)d_in[3];
    const float* ad1 = (const float*)d_in[4];
    const float* b1  = (const float*)d_in[5];
    const float* W2  = (const float*)d_in[6];
    const float* as2 = (const float*)d_in[7];
    const float* ad2 = (const float*)d_in[8];
    const float* b2  = (const float*)d_in[9];
    float* out = (float*)d_out;

    const int N = NNODES;
    const int E = in_sizes[1] / 2;

    // workspace carve-up
    char* ws = (char*)d_ws;
    size_t o = 0;
    auto alloc = [&](size_t bytes) -> void* {
        void* p = ws + o;
        o = (o + bytes + 255) & ~(size_t)255;
        return p;
    };
    int* deg    = (int*)alloc((size_t)N * 4);
    int* off    = (int*)alloc((size_t)(N + 1) * 4);
    int* cursor = (int*)alloc((size_t)N * 4);
    int* slot   = (int*)alloc((size_t)(E + N) * 4);
    float* H1    = (float*)alloc((size_t)N * 64 * 4);
    float* a_s1  = (float*)alloc((size_t)N * 8 * 4);
    float* a_d1  = (float*)alloc((size_t)N * 8 * 4);
    float* H1R   = (float*)alloc((size_t)N * 64 * 4);
    float* H2    = (float*)alloc((size_t)N * 40 * 4);
    float* a_s2  = (float*)alloc((size_t)N * 4);
    float* a_d2  = (float*)alloc((size_t)N * 4);
    (void)ws_size; (void)n_in; (void)out_size;

    // CSR build (shared by both layers)
    init_deg<<<(N + 255) / 256, 256, 0, stream>>>(deg, N);
    count_deg<<<(E + 255) / 256, 256, 0, stream>>>(ei, E, deg);
    scan_deg<<<1, 1024, 0, stream>>>(deg, off, cursor, N);
    scatter_edges<<<(E + N + 255) / 256, 256, 0, stream>>>(ei, E, N, cursor, slot);

    // Layer 1
    gemm1<<<(N + 63) / 64, 256, 0, stream>>>(x, W1, H1, N);
    att1_kernel<<<(N * 8 + 255) / 256, 256, 0, stream>>>(H1, as1, ad1, a_s1, a_d1, N);
    agg1<<<N / 4, 256, 0, stream>>>(off, slot, H1, a_s1, a_d1, b1, H1R);

    // Layer 2
    gemm2_att2<<<N / 4, 256, 0, stream>>>(H1R, W2, as2, ad2, H2, a_s2, a_d2);
    agg2<<<N / 4, 256, 0, stream>>>(off, slot, H2, a_s2, a_d2, b2, out);
}

// Round 2
// 690.333 us; speedup vs baseline: 1.2593x; 1.2593x over previous
//
#include <hip/hip_runtime.h>
#include <math.h>

#define NNODES 50000
#define NEG_SLOPE 0.2f

// ---------------------------------------------------------------------------
// CSR build
// ---------------------------------------------------------------------------
__global__ void init_deg(int* deg, int N) {
    int i = blockIdx.x * 256 + threadIdx.x;
    if (i < N) deg[i] = 1;  // self-loop
}

__global__ void count_deg(const int* __restrict__ ei, int E, int* deg) {
    int e = blockIdx.x * 256 + threadIdx.x;
    if (e < E) atomicAdd(&deg[ei[E + e]], 1);  // row 1 = dst
}

// single-block exclusive scan of deg[N] -> off[N+1], cursor[N]
__global__ __launch_bounds__(1024) void scan_deg(const int* __restrict__ deg,
                                                 int* off, int* cursor, int N) {
    __shared__ int sdata[1024];
    int t = threadIdx.x;
    int chunk = (N + 1023) >> 10;
    int base = t * chunk;
    int lim = min(base + chunk, N);
    int s = 0;
    for (int i = base; i < lim; ++i) s += deg[i];
    sdata[t] = s;
    __syncthreads();
    for (int o = 1; o < 1024; o <<= 1) {
        int v = (t >= o) ? sdata[t - o] : 0;
        __syncthreads();
        sdata[t] += v;
        __syncthreads();
    }
    int run = sdata[t] - s;  // exclusive
    for (int i = base; i < lim; ++i) {
        off[i] = run; cursor[i] = run; run += deg[i];
    }
    if (t == 1023) off[N] = sdata[1023];
}

__global__ void scatter_edges(const int* __restrict__ ei, int E, int N,
                              int* cursor, int* __restrict__ slot) {
    int e = blockIdx.x * 256 + threadIdx.x;
    if (e >= E + N) return;
    int s, d;
    if (e < E) { s = ei[e]; d = ei[E + e]; }
    else       { s = e - E; d = e - E; }       // self-loops
    int pos = atomicAdd(&cursor[d], 1);
    slot[pos] = s;
}

// ---------------------------------------------------------------------------
// GEMM1: H1[M,64] = X[M,512] @ W1[512,64]   (f32, tiled 64x64, 4x4 microtile)
// ---------------------------------------------------------------------------
__global__ __launch_bounds__(256) void gemm1(const float* __restrict__ X,
                                             const float* __restrict__ W,
                                             float* __restrict__ H, int M) {
    __shared__ float As[32][64];  // [k][m]
    __shared__ float Bs[32][64];  // [k][n]
    int tid = threadIdx.x;
    int m0 = blockIdx.x * 64;
    int tc = tid & 15;   // col group (n = tc*4..+3)
    int tr = tid >> 4;   // row group (m = tr*4..+3)
    float acc[4][4] = {};
    for (int k0 = 0; k0 < 512; k0 += 32) {
        // load A tile (transpose into [k][m])
        int kb = (tid & 7) * 4;
        int r = tid >> 3;  // 0..31
        for (int rr = r; rr < 64; rr += 32) {
            int gm = m0 + rr;
            float4 v = make_float4(0.f, 0.f, 0.f, 0.f);
            if (gm < M) v = *(const float4*)(X + (size_t)gm * 512 + k0 + kb);
            As[kb + 0][rr] = v.x; As[kb + 1][rr] = v.y;
            As[kb + 2][rr] = v.z; As[kb + 3][rr] = v.w;
        }
        // load B tile
        int n4 = (tid & 15) * 4;
        int kk = tid >> 4;  // 0..15
        for (int k2 = kk; k2 < 32; k2 += 16) {
            float4 v = *(const float4*)(W + (size_t)(k0 + k2) * 64 + n4);
            *(float4*)&Bs[k2][n4] = v;
        }
        __syncthreads();
#pragma unroll
        for (int k = 0; k < 32; ++k) {
            float4 a4 = *(const float4*)&As[k][tr * 4];
            float4 b4 = *(const float4*)&Bs[k][tc * 4];
            float a[4] = {a4.x, a4.y, a4.z, a4.w};
            float b[4] = {b4.x, b4.y, b4.z, b4.w};
#pragma unroll
            for (int i = 0; i < 4; ++i)
#pragma unroll
                for (int j = 0; j < 4; ++j) acc[i][j] += a[i] * b[j];
        }
        __syncthreads();
    }
#pragma unroll
    for (int i = 0; i < 4; ++i) {
        int gm = m0 + tr * 4 + i;
        if (gm < M)
            *(float4*)(H + (size_t)gm * 64 + tc * 4) =
                make_float4(acc[i][0], acc[i][1], acc[i][2], acc[i][3]);
    }
}

// ---------------------------------------------------------------------------
// att1: a_src1[n,h], a_dst1[n,h] from H1[n, h*8+c]
// ---------------------------------------------------------------------------
__global__ void att1_kernel(const float* __restrict__ H1,
                            const float* __restrict__ att_src,
                            const float* __restrict__ att_dst,
                            float* __restrict__ a_src, float* __restrict__ a_dst,
                            int N) {
    int idx = blockIdx.x * 256 + threadIdx.x;  // idx = n*8 + h
    if (idx >= N * 8) return;
    int h = idx & 7;
    const float* hp = H1 + (size_t)idx * 8;
    float4 h0 = *(const float4*)hp;
    float4 h1v = *(const float4*)(hp + 4);
    const float* sp = att_src + h * 8;
    const float* dp = att_dst + h * 8;
    float4 s0 = *(const float4*)sp, s1 = *(const float4*)(sp + 4);
    float4 d0 = *(const float4*)dp, d1 = *(const float4*)(dp + 4);
    float as = h0.x * s0.x + h0.y * s0.y + h0.z * s0.z + h0.w * s0.w +
               h1v.x * s1.x + h1v.y * s1.y + h1v.z * s1.z + h1v.w * s1.w;
    float ad = h0.x * d0.x + h0.y * d0.y + h0.z * d0.z + h0.w * d0.w +
               h1v.x * d1.x + h1v.y * d1.y + h1v.z * d1.z + h1v.w * d1.w;
    a_src[idx] = as;
    a_dst[idx] = ad;
}

// ---------------------------------------------------------------------------
// agg1: wave per dst node, single pass (softmax normalization applied at end).
// Chunks of 8 edges: compute-role lane = (edge_sub = lane>>3, head = lane&7)
// computes one distinct w = exp(leaky(e)); acc-role lane = feature h*8+c
// broadcasts w/slot via shfl and gathers the coalesced 256B H1 row.
// |e| small (att vectors ~0.5 std) so exp without max-subtraction is safe.
// ---------------------------------------------------------------------------
__global__ __launch_bounds__(256) void agg1(const int* __restrict__ off,
                                            const int* __restrict__ slot,
                                            const float* __restrict__ H1,
                                            const float* __restrict__ a_src,
                                            const float* __restrict__ a_dst,
                                            const float* __restrict__ b1,
                                            float* __restrict__ H1R) {
    int wid = threadIdx.x >> 6, lane = threadIdx.x & 63;
    int d = blockIdx.x * 4 + wid;  // grid exact: 12500*4 = 50000
    int beg = off[d], end = off[d + 1];
    int h = lane >> 3;   // acc-role head (feature index = lane)
    int eh = lane & 7;   // compute-role head
    int es = lane >> 3;  // compute-role edge sub-index
    float adst_c = a_dst[(size_t)d * 8 + eh];
    float acc = 0.f, den = 0.f;
    for (int i = beg; i < end; i += 8) {
        int j = i + es;
        int jj = (j < end) ? j : (end - 1);
        int s = slot[jj];
        float e = a_src[(size_t)s * 8 + eh] + adst_c;
        e = (e >= 0.f) ? e : NEG_SLOPE * e;
        float w = (j < end) ? __expf(e) : 0.f;
#pragma unroll
        for (int q = 0; q < 8; ++q) {
            int sq = __shfl(s, q << 3);
            float wq = __shfl(w, (q << 3) | h);
            acc += wq * H1[(size_t)sq * 64 + lane];
            den += wq;
        }
    }
    float v = acc / (den + 1e-16f) + b1[lane];
    H1R[(size_t)d * 64 + lane] = (v > 0.f) ? v : 0.f;
}

// ---------------------------------------------------------------------------
// GEMM2 + att2 fused: wave per node. H2[n,40] = H1R[n,:] @ W2[64,40];
// a_src2[n] = H2[n,:].att_src2 ; a_dst2[n] = H2[n,:].att_dst2
// ---------------------------------------------------------------------------
__global__ __launch_bounds__(256) void gemm2_att2(const float* __restrict__ H1R,
                                                  const float* __restrict__ W2,
                                                  const float* __restrict__ att_src2,
                                                  const float* __restrict__ att_dst2,
                                                  float* __restrict__ H2,
                                                  float* __restrict__ a_src2,
                                                  float* __restrict__ a_dst2) {
    __shared__ float W2s[64 * 40];
    __shared__ float rows[4][64];
    int tid = threadIdx.x;
    int wid = tid >> 6, lane = tid & 63;
    for (int i = tid; i < 64 * 40; i += 256) W2s[i] = W2[i];
    int node = blockIdx.x * 4 + wid;  // grid exact
    rows[wid][lane] = H1R[(size_t)node * 64 + lane];
    __syncthreads();
    int c = lane;
    int cc = (c < 40) ? c : 0;
    float acc = 0.f;
#pragma unroll 8
    for (int k = 0; k < 64; ++k) acc += rows[wid][k] * W2s[k * 40 + cc];
    if (c < 40) H2[(size_t)node * 40 + c] = acc;
    float ps = (c < 40) ? acc * att_src2[c] : 0.f;
    float pd = (c < 40) ? acc * att_dst2[c] : 0.f;
#pragma unroll
    for (int m = 32; m >= 1; m >>= 1) {
        ps += __shfl_xor(ps, m);
        pd += __shfl_xor(pd, m);
    }
    if (lane == 0) { a_src2[node] = ps; a_dst2[node] = pd; }
}

// ---------------------------------------------------------------------------
// agg2 + bias + log_softmax: wave per dst node, single pass, 64-edge chunks.
// Each lane computes one distinct w; inner loop (groups of 8, early-exit)
// broadcasts w/slot and gathers H2 rows (lane = channel, 40 active).
// ---------------------------------------------------------------------------
__global__ __launch_bounds__(256) void agg2(const int* __restrict__ off,
                                            const int* __restrict__ slot,
                                            const float* __restrict__ H2,
                                            const float* __restrict__ a_src2,
                                            const float* __restrict__ a_d2,
                                            const float* __restrict__ b2,
                                            float* __restrict__ out) {
    int wid = threadIdx.x >> 6, lane = threadIdx.x & 63;
    int d = blockIdx.x * 4 + wid;  // grid exact
    int beg = off[d], end = off[d + 1];
    float adst = a_d2[d];
    int c = lane;
    int cc = (c < 40) ? c : 0;
    float acc = 0.f, den = 0.f;
    for (int i = beg; i < end; i += 64) {
        int j = i + lane;
        int jj = (j < end) ? j : (end - 1);
        int s = slot[jj];
        float e = a_src2[s] + adst;
        e = (e >= 0.f) ? e : NEG_SLOPE * e;
        float w = (j < end) ? __expf(e) : 0.f;
#pragma unroll
        for (int qb = 0; qb < 8; ++qb) {
            if (i + (qb << 3) >= end) break;  // uniform branch
#pragma unroll
            for (int qq = 0; qq < 8; ++qq) {
                int q = (qb << 3) + qq;
                int sq = __shfl(s, q);
                float wq = __shfl(w, q);
                acc += wq * H2[(size_t)sq * 40 + cc];
                den += wq;
            }
        }
    }
    float v = acc / (den + 1e-16f) + b2[cc];
    // log_softmax over 40 channels
    float vm = (c < 40) ? v : -3.0e38f;
#pragma unroll
    for (int m = 32; m >= 1; m >>= 1) vm = fmaxf(vm, __shfl_xor(vm, m));
    float se = (c < 40) ? __expf(v - vm) : 0.f;
#pragma unroll
    for (int m = 32; m >= 1; m >>= 1) se += __shfl_xor(se, m);
    float res = v - vm - __logf(se);
    if (c < 40) out[(size_t)d * 40 + c] = res;
}

// ---------------------------------------------------------------------------
extern "C" void kernel_launch(void* const* d_in, const int* in_sizes, int n_in,
                              void* d_out, int out_size, void* d_ws, size_t ws_size,
                              hipStream_t stream) {
    const float* x   = (const float*)d_in[0];
    const int*   ei  = (const int*)d_in[1];
    const float* W1  = (const float*)d_in[2];
    const float* as1 = (const float*)d_in[3];
    const float* ad1 = (const float*)d_in[4];
    const float* b1  = (const float*)d_in[5];
    const float* W2  = (const float*)d_in[6];
    const float* as2 = (const float*)d_in[7];
    const float* ad2 = (const float*)d_in[8];
    const float* b2  = (const float*)d_in[9];
    float* out = (float*)d_out;

    const int N = NNODES;
    const int E = in_sizes[1] / 2;

    // workspace carve-up
    char* ws = (char*)d_ws;
    size_t o = 0;
    auto alloc = [&](size_t bytes) -> void* {
        void* p = ws + o;
        o = (o + bytes + 255) & ~(size_t)255;
        return p;
    };
    int* deg    = (int*)alloc((size_t)N * 4);
    int* off    = (int*)alloc((size_t)(N + 1) * 4);
    int* cursor = (int*)alloc((size_t)N * 4);
    int* slot   = (int*)alloc((size_t)(E + N) * 4);
    float* H1    = (float*)alloc((size_t)N * 64 * 4);
    float* a_s1  = (float*)alloc((size_t)N * 8 * 4);
    float* a_d1  = (float*)alloc((size_t)N * 8 * 4);
    float* H1R   = (float*)alloc((size_t)N * 64 * 4);
    float* H2    = (float*)alloc((size_t)N * 40 * 4);
    float* a_s2  = (float*)alloc((size_t)N * 4);
    float* a_d2  = (float*)alloc((size_t)N * 4);
    (void)ws_size; (void)n_in; (void)out_size;

    // CSR build (shared by both layers)
    init_deg<<<(N + 255) / 256, 256, 0, stream>>>(deg, N);
    count_deg<<<(E + 255) / 256, 256, 0, stream>>>(ei, E, deg);
    scan_deg<<<1, 1024, 0, stream>>>(deg, off, cursor, N);
    scatter_edges<<<(E + N + 255) / 256, 256, 0, stream>>>(ei, E, N, cursor, slot);

    // Layer 1
    gemm1<<<(N + 63) / 64, 256, 0, stream>>>(x, W1, H1, N);
    att1_kernel<<<(N * 8 + 255) / 256, 256, 0, stream>>>(H1, as1, ad1, a_s1, a_d1, N);
    agg1<<<N / 4, 256, 0, stream>>>(off, slot, H1, a_s1, a_d1, b1, H1R);

    // Layer 2
    gemm2_att2<<<N / 4, 256, 0, stream>>>(H1R, W2, as2, ad2, H2, a_s2, a_d2);
    agg2<<<N / 4, 256, 0, stream>>>(off, slot, H2, a_s2, a_d2, b2, out);
}

// Round 3
// 451.693 us; speedup vs baseline: 1.9246x; 1.5283x over previous
//
#include <hip/hip_runtime.h>
#include <math.h>

#define NNODES 50000
#define NEG_SLOPE 0.2f
#define NB 391      // ceil(50000/128) buckets
#define BW 128      // nodes per bucket
#define CHUNK 8192  // edges per block in bin_scatter

// ---------------------------------------------------------------------------
// CSR build: two-level binned counting sort (avoids random 4B HBM scatter).
// ---------------------------------------------------------------------------
__global__ __launch_bounds__(256) void bucket_count(const int* __restrict__ ei,
                                                    int E, int N, int* bcnt) {
    __shared__ int h[NB];
    int tid = threadIdx.x;
    for (int i = tid; i < NB; i += 256) h[i] = 0;
    __syncthreads();
    int total = E + N, stride = gridDim.x * 256;
    for (int e = blockIdx.x * 256 + tid; e < total; e += stride) {
        int d = (e < E) ? ei[E + e] : e - E;  // row 1 = dst; tail = self-loops
        atomicAdd(&h[d >> 7], 1);
    }
    __syncthreads();
    for (int i = tid; i < NB; i += 256)
        if (h[i]) atomicAdd(&bcnt[i], h[i]);
}

__global__ __launch_bounds__(512) void scan_buckets(const int* __restrict__ bcnt,
                                                    int* bbase, int* bcur,
                                                    int* off, int N, int total) {
    __shared__ int s[512];
    int t = threadIdx.x;
    int v = (t < NB) ? bcnt[t] : 0;
    s[t] = v;
    __syncthreads();
    for (int o = 1; o < 512; o <<= 1) {
        int u = (t >= o) ? s[t - o] : 0;
        __syncthreads();
        s[t] += u;
        __syncthreads();
    }
    if (t < NB) { int ex = s[t] - v; bbase[t] = ex; bcur[t] = ex; }
    if (t == 0) off[N] = total;
}

// Per-block: LDS bucket histogram -> one reservation atomic per bucket ->
// write packed (dst&127)<<16|src into block-private contiguous runs of tmp.
__global__ __launch_bounds__(256) void bin_scatter(const int* __restrict__ ei,
                                                   int E, int N, int* bcur,
                                                   int* __restrict__ tmp) {
    __shared__ int lcnt[NB];
    __shared__ int lbase[NB];
    int tid = threadIdx.x;
    int base0 = blockIdx.x * CHUNK;
    int lim = min(base0 + CHUNK, E + N);
    for (int i = tid; i < NB; i += 256) lcnt[i] = 0;
    __syncthreads();
    for (int e = base0 + tid; e < lim; e += 256) {
        int d = (e < E) ? ei[E + e] : e - E;
        atomicAdd(&lcnt[d >> 7], 1);
    }
    __syncthreads();
    for (int b = tid; b < NB; b += 256) {
        int c = lcnt[b];
        lbase[b] = c ? atomicAdd(&bcur[b], c) : 0;
    }
    __syncthreads();
    for (int i = tid; i < NB; i += 256) lcnt[i] = 0;
    __syncthreads();
    for (int e = base0 + tid; e < lim; e += 256) {
        int s, d;
        if (e < E) { s = ei[e]; d = ei[E + e]; }
        else       { s = d = e - E; }
        int b = d >> 7;
        int p = atomicAdd(&lcnt[b], 1);
        tmp[lbase[b] + p] = ((d & 127) << 16) | s;  // src < 50000 < 2^16
    }
}

// One block per bucket: per-node LDS count + scan -> off[], then localized
// scatter into slot (single-XCD ~16KB region -> full-line L2 write-backs).
__global__ __launch_bounds__(256) void csr_finalize(const int* __restrict__ bbase,
                                                    const int* __restrict__ bcnt,
                                                    const int* __restrict__ tmp,
                                                    int N, int* __restrict__ off,
                                                    int* __restrict__ slot) {
    __shared__ int cnt[BW];
    __shared__ int cur[BW];
    int b = blockIdx.x, tid = threadIdx.x;
    int base = bbase[b], m = bcnt[b];
    if (tid < BW) cnt[tid] = 0;
    __syncthreads();
    for (int i = tid; i < m; i += 256)
        atomicAdd(&cnt[(tmp[base + i] >> 16) & 127], 1);
    __syncthreads();
    int myv = (tid < BW) ? cnt[tid] : 0;
    for (int o = 1; o < BW; o <<= 1) {
        int u = 0;
        if (tid >= o && tid < BW) u = cnt[tid - o];
        __syncthreads();
        if (tid < BW) cnt[tid] += u;
        __syncthreads();
    }
    if (tid < BW) {
        int ex = base + cnt[tid] - myv;  // exclusive
        cur[tid] = ex;
        int g = b * BW + tid;
        if (g < N) off[g] = ex;
    }
    __syncthreads();
    for (int i = tid; i < m; i += 256) {
        int v = tmp[base + i];
        int k = (v >> 16) & 127;
        int p = atomicAdd(&cur[k], 1);
        slot[p] = v & 0xFFFF;
    }
}

// ---------------------------------------------------------------------------
// GEMM1: H1[M,64] = X[M,512] @ W1[512,64]   (f32, tiled 64x64, 4x4 microtile)
// ---------------------------------------------------------------------------
__global__ __launch_bounds__(256) void gemm1(const float* __restrict__ X,
                                             const float* __restrict__ W,
                                             float* __restrict__ H, int M) {
    __shared__ float As[32][64];  // [k][m]
    __shared__ float Bs[32][64];  // [k][n]
    int tid = threadIdx.x;
    int m0 = blockIdx.x * 64;
    int tc = tid & 15;   // col group (n = tc*4..+3)
    int tr = tid >> 4;   // row group (m = tr*4..+3)
    float acc[4][4] = {};
    for (int k0 = 0; k0 < 512; k0 += 32) {
        int kb = (tid & 7) * 4;
        int r = tid >> 3;  // 0..31
        for (int rr = r; rr < 64; rr += 32) {
            int gm = m0 + rr;
            float4 v = make_float4(0.f, 0.f, 0.f, 0.f);
            if (gm < M) v = *(const float4*)(X + (size_t)gm * 512 + k0 + kb);
            As[kb + 0][rr] = v.x; As[kb + 1][rr] = v.y;
            As[kb + 2][rr] = v.z; As[kb + 3][rr] = v.w;
        }
        int n4 = (tid & 15) * 4;
        int kk = tid >> 4;  // 0..15
        for (int k2 = kk; k2 < 32; k2 += 16) {
            float4 v = *(const float4*)(W + (size_t)(k0 + k2) * 64 + n4);
            *(float4*)&Bs[k2][n4] = v;
        }
        __syncthreads();
#pragma unroll
        for (int k = 0; k < 32; ++k) {
            float4 a4 = *(const float4*)&As[k][tr * 4];
            float4 b4 = *(const float4*)&Bs[k][tc * 4];
            float a[4] = {a4.x, a4.y, a4.z, a4.w};
            float b[4] = {b4.x, b4.y, b4.z, b4.w};
#pragma unroll
            for (int i = 0; i < 4; ++i)
#pragma unroll
                for (int j = 0; j < 4; ++j) acc[i][j] += a[i] * b[j];
        }
        __syncthreads();
    }
#pragma unroll
    for (int i = 0; i < 4; ++i) {
        int gm = m0 + tr * 4 + i;
        if (gm < M)
            *(float4*)(H + (size_t)gm * 64 + tc * 4) =
                make_float4(acc[i][0], acc[i][1], acc[i][2], acc[i][3]);
    }
}

// ---------------------------------------------------------------------------
// att1: a_src1[n,h], a_dst1[n,h] from H1[n, h*8+c]
// ---------------------------------------------------------------------------
__global__ void att1_kernel(const float* __restrict__ H1,
                            const float* __restrict__ att_src,
                            const float* __restrict__ att_dst,
                            float* __restrict__ a_src, float* __restrict__ a_dst,
                            int N) {
    int idx = blockIdx.x * 256 + threadIdx.x;  // idx = n*8 + h
    if (idx >= N * 8) return;
    int h = idx & 7;
    const float* hp = H1 + (size_t)idx * 8;
    float4 h0 = *(const float4*)hp;
    float4 h1v = *(const float4*)(hp + 4);
    const float* sp = att_src + h * 8;
    const float* dp = att_dst + h * 8;
    float4 s0 = *(const float4*)sp, s1 = *(const float4*)(sp + 4);
    float4 d0 = *(const float4*)dp, d1 = *(const float4*)(dp + 4);
    float as = h0.x * s0.x + h0.y * s0.y + h0.z * s0.z + h0.w * s0.w +
               h1v.x * s1.x + h1v.y * s1.y + h1v.z * s1.z + h1v.w * s1.w;
    float ad = h0.x * d0.x + h0.y * d0.y + h0.z * d0.z + h0.w * d0.w +
               h1v.x * d1.x + h1v.y * d1.y + h1v.z * d1.z + h1v.w * d1.w;
    a_src[idx] = as;
    a_dst[idx] = ad;
}

// ---------------------------------------------------------------------------
// agg1: wave per dst node, single pass (softmax normalization applied at end).
// ---------------------------------------------------------------------------
__global__ __launch_bounds__(256) void agg1(const int* __restrict__ off,
                                            const int* __restrict__ slot,
                                            const float* __restrict__ H1,
                                            const float* __restrict__ a_src,
                                            const float* __restrict__ a_dst,
                                            const float* __restrict__ b1,
                                            float* __restrict__ H1R) {
    int wid = threadIdx.x >> 6, lane = threadIdx.x & 63;
    int d = blockIdx.x * 4 + wid;  // grid exact: 12500*4 = 50000
    int beg = off[d], end = off[d + 1];
    int h = lane >> 3;   // acc-role head (feature index = lane)
    int eh = lane & 7;   // compute-role head
    int es = lane >> 3;  // compute-role edge sub-index
    float adst_c = a_dst[(size_t)d * 8 + eh];
    float acc = 0.f, den = 0.f;
    for (int i = beg; i < end; i += 8) {
        int j = i + es;
        int jj = (j < end) ? j : (end - 1);
        int s = slot[jj];
        float e = a_src[(size_t)s * 8 + eh] + adst_c;
        e = (e >= 0.f) ? e : NEG_SLOPE * e;
        float w = (j < end) ? __expf(e) : 0.f;
#pragma unroll
        for (int q = 0; q < 8; ++q) {
            int sq = __shfl(s, q << 3);
            float wq = __shfl(w, (q << 3) | h);
            acc += wq * H1[(size_t)sq * 64 + lane];
            den += wq;
        }
    }
    float v = acc / (den + 1e-16f) + b1[lane];
    H1R[(size_t)d * 64 + lane] = (v > 0.f) ? v : 0.f;
}

// ---------------------------------------------------------------------------
// GEMM2 + att2 fused: wave per node.
// ---------------------------------------------------------------------------
__global__ __launch_bounds__(256) void gemm2_att2(const float* __restrict__ H1R,
                                                  const float* __restrict__ W2,
                                                  const float* __restrict__ att_src2,
                                                  const float* __restrict__ att_dst2,
                                                  float* __restrict__ H2,
                                                  float* __restrict__ a_src2,
                                                  float* __restrict__ a_dst2) {
    __shared__ float W2s[64 * 40];
    __shared__ float rows[4][64];
    int tid = threadIdx.x;
    int wid = tid >> 6, lane = tid & 63;
    for (int i = tid; i < 64 * 40; i += 256) W2s[i] = W2[i];
    int node = blockIdx.x * 4 + wid;  // grid exact
    rows[wid][lane] = H1R[(size_t)node * 64 + lane];
    __syncthreads();
    int c = lane;
    int cc = (c < 40) ? c : 0;
    float acc = 0.f;
#pragma unroll 8
    for (int k = 0; k < 64; ++k) acc += rows[wid][k] * W2s[k * 40 + cc];
    if (c < 40) H2[(size_t)node * 40 + c] = acc;
    float ps = (c < 40) ? acc * att_src2[c] : 0.f;
    float pd = (c < 40) ? acc * att_dst2[c] : 0.f;
#pragma unroll
    for (int m = 32; m >= 1; m >>= 1) {
        ps += __shfl_xor(ps, m);
        pd += __shfl_xor(pd, m);
    }
    if (lane == 0) { a_src2[node] = ps; a_dst2[node] = pd; }
}

// ---------------------------------------------------------------------------
// agg2 + bias + log_softmax: wave per dst node, single pass, 64-edge chunks.
// ---------------------------------------------------------------------------
__global__ __launch_bounds__(256) void agg2(const int* __restrict__ off,
                                            const int* __restrict__ slot,
                                            const float* __restrict__ H2,
                                            const float* __restrict__ a_src2,
                                            const float* __restrict__ a_d2,
                                            const float* __restrict__ b2,
                                            float* __restrict__ out) {
    int wid = threadIdx.x >> 6, lane = threadIdx.x & 63;
    int d = blockIdx.x * 4 + wid;  // grid exact
    int beg = off[d], end = off[d + 1];
    float adst = a_d2[d];
    int c = lane;
    int cc = (c < 40) ? c : 0;
    float acc = 0.f, den = 0.f;
    for (int i = beg; i < end; i += 64) {
        int j = i + lane;
        int jj = (j < end) ? j : (end - 1);
        int s = slot[jj];
        float e = a_src2[s] + adst;
        e = (e >= 0.f) ? e : NEG_SLOPE * e;
        float w = (j < end) ? __expf(e) : 0.f;
#pragma unroll
        for (int qb = 0; qb < 8; ++qb) {
            if (i + (qb << 3) >= end) break;  // uniform branch
#pragma unroll
            for (int qq = 0; qq < 8; ++qq) {
                int q = (qb << 3) + qq;
                int sq = __shfl(s, q);
                float wq = __shfl(w, q);
                acc += wq * H2[(size_t)sq * 40 + cc];
                den += wq;
            }
        }
    }
    float v = acc / (den + 1e-16f) + b2[cc];
    float vm = (c < 40) ? v : -3.0e38f;
#pragma unroll
    for (int m = 32; m >= 1; m >>= 1) vm = fmaxf(vm, __shfl_xor(vm, m));
    float se = (c < 40) ? __expf(v - vm) : 0.f;
#pragma unroll
    for (int m = 32; m >= 1; m >>= 1) se += __shfl_xor(se, m);
    float res = v - vm - __logf(se);
    if (c < 40) out[(size_t)d * 40 + c] = res;
}

// ---------------------------------------------------------------------------
extern "C" void kernel_launch(void* const* d_in, const int* in_sizes, int n_in,
                              void* d_out, int out_size, void* d_ws, size_t ws_size,
                              hipStream_t stream) {
    const float* x   = (const float*)d_in[0];
    const int*   ei  = (const int*)d_in[1];
    const float* W1  = (const float*)d_in[2];
    const float* as1 = (const float*)d_in[3];
    const float* ad1 = (const float*)d_in[4];
    const float* b1  = (const float*)d_in[5];
    const float* W2  = (const float*)d_in[6];
    const float* as2 = (const float*)d_in[7];
    const float* ad2 = (const float*)d_in[8];
    const float* b2  = (const float*)d_in[9];
    float* out = (float*)d_out;

    const int N = NNODES;
    const int E = in_sizes[1] / 2;
    const int total = E + N;

    // workspace carve-up
    char* ws = (char*)d_ws;
    size_t o = 0;
    auto alloc = [&](size_t bytes) -> void* {
        void* p = ws + o;
        o = (o + bytes + 255) & ~(size_t)255;
        return p;
    };
    int* bcnt  = (int*)alloc((size_t)NB * 4);
    int* bbase = (int*)alloc((size_t)NB * 4);
    int* bcur  = (int*)alloc((size_t)NB * 4);
    int* off   = (int*)alloc((size_t)(N + 1) * 4);
    int* slot  = (int*)alloc((size_t)total * 4);
    float* H1   = (float*)alloc((size_t)N * 64 * 4);
    float* a_s1 = (float*)alloc((size_t)N * 8 * 4);
    float* a_d1 = (float*)alloc((size_t)N * 8 * 4);
    float* H1R  = (float*)alloc((size_t)N * 64 * 4);
    float* H2   = (float*)alloc((size_t)N * 40 * 4);
    float* a_s2 = (float*)alloc((size_t)N * 4);
    float* a_d2 = (float*)alloc((size_t)N * 4);
    int* tmp = (int*)H1R;  // alias: tmp dead before agg1 writes H1R
    (void)ws_size; (void)n_in; (void)out_size;

    // CSR build (binned counting sort; shared by both layers)
    hipMemsetAsync(bcnt, 0, (size_t)NB * 4, stream);
    bucket_count<<<512, 256, 0, stream>>>(ei, E, N, bcnt);
    scan_buckets<<<1, 512, 0, stream>>>(bcnt, bbase, bcur, off, N, total);
    bin_scatter<<<(total + CHUNK - 1) / CHUNK, 256, 0, stream>>>(ei, E, N, bcur, tmp);
    csr_finalize<<<NB, 256, 0, stream>>>(bbase, bcnt, tmp, N, off, slot);

    // Layer 1
    gemm1<<<(N + 63) / 64, 256, 0, stream>>>(x, W1, H1, N);
    att1_kernel<<<(N * 8 + 255) / 256, 256, 0, stream>>>(H1, as1, ad1, a_s1, a_d1, N);
    agg1<<<N / 4, 256, 0, stream>>>(off, slot, H1, a_s1, a_d1, b1, H1R);

    // Layer 2
    gemm2_att2<<<N / 4, 256, 0, stream>>>(H1R, W2, as2, ad2, H2, a_s2, a_d2);
    agg2<<<N / 4, 256, 0, stream>>>(off, slot, H2, a_s2, a_d2, b2, out);
}

// Round 4
// 404.777 us; speedup vs baseline: 2.1477x; 1.1159x over previous
//
#include <hip/hip_runtime.h>
#include <math.h>

#define NNODES 50000
#define NEG_SLOPE 0.2f
#define NB 391      // ceil(50000/128) buckets
#define BW 128      // nodes per bucket
#define CHUNK 8192  // edges per block in bin_scatter

typedef __bf16 bf16x8 __attribute__((ext_vector_type(8)));
typedef float f32x4 __attribute__((ext_vector_type(4)));

// ---------------------------------------------------------------------------
// CSR build: two-level binned counting sort (avoids random 4B HBM scatter).
// ---------------------------------------------------------------------------
__global__ __launch_bounds__(256) void bucket_count(const int* __restrict__ ei,
                                                    int E, int N, int* bcnt) {
    __shared__ int h[NB];
    int tid = threadIdx.x;
    for (int i = tid; i < NB; i += 256) h[i] = 0;
    __syncthreads();
    int total = E + N, stride = gridDim.x * 256;
    for (int e = blockIdx.x * 256 + tid; e < total; e += stride) {
        int d = (e < E) ? ei[E + e] : e - E;  // row 1 = dst; tail = self-loops
        atomicAdd(&h[d >> 7], 1);
    }
    __syncthreads();
    for (int i = tid; i < NB; i += 256)
        if (h[i]) atomicAdd(&bcnt[i], h[i]);
}

__global__ __launch_bounds__(512) void scan_buckets(const int* __restrict__ bcnt,
                                                    int* bbase, int* bcur,
                                                    int* off, int N, int total) {
    __shared__ int s[512];
    int t = threadIdx.x;
    int v = (t < NB) ? bcnt[t] : 0;
    s[t] = v;
    __syncthreads();
    for (int o = 1; o < 512; o <<= 1) {
        int u = (t >= o) ? s[t - o] : 0;
        __syncthreads();
        s[t] += u;
        __syncthreads();
    }
    if (t < NB) { int ex = s[t] - v; bbase[t] = ex; bcur[t] = ex; }
    if (t == 0) off[N] = total;
}

__global__ __launch_bounds__(256) void bin_scatter(const int* __restrict__ ei,
                                                   int E, int N, int* bcur,
                                                   int* __restrict__ tmp) {
    __shared__ int lcnt[NB];
    __shared__ int lbase[NB];
    int tid = threadIdx.x;
    int base0 = blockIdx.x * CHUNK;
    int lim = min(base0 + CHUNK, E + N);
    for (int i = tid; i < NB; i += 256) lcnt[i] = 0;
    __syncthreads();
    for (int e = base0 + tid; e < lim; e += 256) {
        int d = (e < E) ? ei[E + e] : e - E;
        atomicAdd(&lcnt[d >> 7], 1);
    }
    __syncthreads();
    for (int b = tid; b < NB; b += 256) {
        int c = lcnt[b];
        lbase[b] = c ? atomicAdd(&bcur[b], c) : 0;
    }
    __syncthreads();
    for (int i = tid; i < NB; i += 256) lcnt[i] = 0;
    __syncthreads();
    for (int e = base0 + tid; e < lim; e += 256) {
        int s, d;
        if (e < E) { s = ei[e]; d = ei[E + e]; }
        else       { s = d = e - E; }
        int b = d >> 7;
        int p = atomicAdd(&lcnt[b], 1);
        tmp[lbase[b] + p] = ((d & 127) << 16) | s;  // src < 50000 < 2^16
    }
}

__global__ __launch_bounds__(256) void csr_finalize(const int* __restrict__ bbase,
                                                    const int* __restrict__ bcnt,
                                                    const int* __restrict__ tmp,
                                                    int N, int* __restrict__ off,
                                                    int* __restrict__ slot) {
    __shared__ int cnt[BW];
    __shared__ int cur[BW];
    int b = blockIdx.x, tid = threadIdx.x;
    int base = bbase[b], m = bcnt[b];
    if (tid < BW) cnt[tid] = 0;
    __syncthreads();
    for (int i = tid; i < m; i += 256)
        atomicAdd(&cnt[(tmp[base + i] >> 16) & 127], 1);
    __syncthreads();
    int myv = (tid < BW) ? cnt[tid] : 0;
    for (int o = 1; o < BW; o <<= 1) {
        int u = 0;
        if (tid >= o && tid < BW) u = cnt[tid - o];
        __syncthreads();
        if (tid < BW) cnt[tid] += u;
        __syncthreads();
    }
    if (tid < BW) {
        int ex = base + cnt[tid] - myv;  // exclusive
        cur[tid] = ex;
        int g = b * BW + tid;
        if (g < N) off[g] = ex;
    }
    __syncthreads();
    for (int i = tid; i < m; i += 256) {
        int v = tmp[base + i];
        int k = (v >> 16) & 127;
        int p = atomicAdd(&cur[k], 1);
        slot[p] = v & 0xFFFF;
    }
}

// ---------------------------------------------------------------------------
// prep_w1: W1[512,64] f32 -> bf16, panelized [k/8][n][k%8] for b-fragments.
// ---------------------------------------------------------------------------
__global__ void prep_w1(const float* __restrict__ W1, __bf16* __restrict__ W1b) {
    int i = blockIdx.x * 256 + threadIdx.x;  // over 512*64
    if (i >= 512 * 64) return;
    int k = i >> 6, n = i & 63;
    W1b[((size_t)(k >> 3) * 64 + n) * 8 + (k & 7)] = (__bf16)W1[i];
}

// ---------------------------------------------------------------------------
// gemm1_mfma: H1b[M,64](bf16) = bf16(X[M,512]) @ bf16(W1[512,64]).
// 64-row tile/block, 4 waves; wave w computes rows [16w,16w+16) x all 64 cols
// via mfma_f32_16x16x32_bf16. LDS panels [kchunk][row][8] (frag reads 2-way
// conflict = free). K-loop: 16 steps of BK=32.
// ---------------------------------------------------------------------------
__global__ __launch_bounds__(256) void gemm1_mfma(const float* __restrict__ X,
                                                  const __bf16* __restrict__ W1b,
                                                  __bf16* __restrict__ H1b, int M) {
    __shared__ __bf16 As[2048];  // [kq 0..3][m 0..63][8]
    __shared__ __bf16 Bs[2048];  // [kq 0..3][n 0..63][8]
    int tid = threadIdx.x, wid = tid >> 6, lane = tid & 63;
    int quad = lane >> 4, l15 = lane & 15;
    int m0 = blockIdx.x * 64;
    f32x4 acc[4] = {{0.f, 0.f, 0.f, 0.f}, {0.f, 0.f, 0.f, 0.f},
                    {0.f, 0.f, 0.f, 0.f}, {0.f, 0.f, 0.f, 0.f}};
    int mrow = tid >> 2;   // 0..63 (staging role)
    int kq_w = tid & 3;    // k-chunk (staging role)
    int xrow = min(m0 + mrow, M - 1);  // clamp: garbage rows never stored
    const float* xp = X + (size_t)xrow * 512 + kq_w * 8;
    for (int kb = 0; kb < 16; ++kb) {
        // stage A: 8 f32 -> 8 bf16 (128B/row coalesced per 4 lanes)
        float4 xa = *(const float4*)(xp + kb * 32);
        float4 xb = *(const float4*)(xp + kb * 32 + 4);
        bf16x8 av;
        av[0] = (__bf16)xa.x; av[1] = (__bf16)xa.y;
        av[2] = (__bf16)xa.z; av[3] = (__bf16)xa.w;
        av[4] = (__bf16)xb.x; av[5] = (__bf16)xb.y;
        av[6] = (__bf16)xb.z; av[7] = (__bf16)xb.w;
        *(bf16x8*)(As + ((size_t)kq_w * 64 + mrow) * 8) = av;
        // stage B: 1KB/wave contiguous, lane-linear (conflict-free)
        *(bf16x8*)(Bs + ((size_t)wid * 64 + lane) * 8) =
            *(const bf16x8*)(W1b + ((size_t)(kb * 4 + wid) * 64 + lane) * 8);
        __syncthreads();
        // a-frag: A[m=16*wid+l15][k=quad*8+j]
        bf16x8 af = *(const bf16x8*)(As + ((size_t)quad * 64 + 16 * wid + l15) * 8);
#pragma unroll
        for (int t = 0; t < 4; ++t) {
            bf16x8 bf = *(const bf16x8*)(Bs + ((size_t)quad * 64 + 16 * t + l15) * 8);
            acc[t] = __builtin_amdgcn_mfma_f32_16x16x32_bf16(af, bf, acc[t], 0, 0, 0);
        }
        __syncthreads();
    }
    // epilogue: D[row=quad*4+r][col=l15] per n-tile t
#pragma unroll
    for (int t = 0; t < 4; ++t) {
#pragma unroll
        for (int r = 0; r < 4; ++r) {
            int gm = m0 + 16 * wid + quad * 4 + r;
            if (gm < M) H1b[(size_t)gm * 64 + 16 * t + l15] = (__bf16)acc[t][r];
        }
    }
}

// ---------------------------------------------------------------------------
// att1: a_src1[n,h], a_dst1[n,h] from H1b[n, h*8+c] (bf16)
// ---------------------------------------------------------------------------
__global__ void att1_kernel(const __bf16* __restrict__ H1b,
                            const float* __restrict__ att_src,
                            const float* __restrict__ att_dst,
                            float* __restrict__ a_src, float* __restrict__ a_dst,
                            int N) {
    int idx = blockIdx.x * 256 + threadIdx.x;  // idx = n*8 + h
    if (idx >= N * 8) return;
    int h = idx & 7;
    bf16x8 hv = *(const bf16x8*)(H1b + (size_t)idx * 8);
    const float* sp = att_src + h * 8;
    const float* dp = att_dst + h * 8;
    float as = 0.f, ad = 0.f;
#pragma unroll
    for (int j = 0; j < 8; ++j) {
        float hf = (float)hv[j];
        as += hf * sp[j];
        ad += hf * dp[j];
    }
    a_src[idx] = as;
    a_dst[idx] = ad;
}

// ---------------------------------------------------------------------------
// agg1: wave per dst node, single pass. bf16 H1 gathers (128B/row).
// ---------------------------------------------------------------------------
__global__ __launch_bounds__(256) void agg1(const int* __restrict__ off,
                                            const int* __restrict__ slot,
                                            const __bf16* __restrict__ H1b,
                                            const float* __restrict__ a_src,
                                            const float* __restrict__ a_dst,
                                            const float* __restrict__ b1,
                                            float* __restrict__ H1R) {
    int wid = threadIdx.x >> 6, lane = threadIdx.x & 63;
    int d = blockIdx.x * 4 + wid;  // grid exact: 12500*4 = 50000
    int beg = off[d], end = off[d + 1];
    int h = lane >> 3;   // acc-role head (feature index = lane)
    int eh = lane & 7;   // compute-role head
    int es = lane >> 3;  // compute-role edge sub-index
    float adst_c = a_dst[(size_t)d * 8 + eh];
    float acc = 0.f, den = 0.f;
    for (int i = beg; i < end; i += 8) {
        int j = i + es;
        int jj = (j < end) ? j : (end - 1);
        int s = slot[jj];
        float e = a_src[(size_t)s * 8 + eh] + adst_c;
        e = (e >= 0.f) ? e : NEG_SLOPE * e;
        float w = (j < end) ? __expf(e) : 0.f;
#pragma unroll
        for (int q = 0; q < 8; ++q) {
            int sq = __shfl(s, q << 3);
            float wq = __shfl(w, (q << 3) | h);
            acc += wq * (float)H1b[(size_t)sq * 64 + lane];
            den += wq;
        }
    }
    float v = acc / (den + 1e-16f) + b1[lane];
    H1R[(size_t)d * 64 + lane] = (v > 0.f) ? v : 0.f;
}

// ---------------------------------------------------------------------------
// GEMM2 + att2 fused: wave per node. H2b bf16 out.
// ---------------------------------------------------------------------------
__global__ __launch_bounds__(256) void gemm2_att2(const float* __restrict__ H1R,
                                                  const float* __restrict__ W2,
                                                  const float* __restrict__ att_src2,
                                                  const float* __restrict__ att_dst2,
                                                  __bf16* __restrict__ H2b,
                                                  float* __restrict__ a_src2,
                                                  float* __restrict__ a_dst2) {
    __shared__ float W2s[64 * 40];
    __shared__ float rows[4][64];
    int tid = threadIdx.x;
    int wid = tid >> 6, lane = tid & 63;
    for (int i = tid; i < 64 * 40; i += 256) W2s[i] = W2[i];
    int node = blockIdx.x * 4 + wid;  // grid exact
    rows[wid][lane] = H1R[(size_t)node * 64 + lane];
    __syncthreads();
    int c = lane;
    int cc = (c < 40) ? c : 0;
    float acc = 0.f;
#pragma unroll 8
    for (int k = 0; k < 64; ++k) acc += rows[wid][k] * W2s[k * 40 + cc];
    if (c < 40) H2b[(size_t)node * 40 + c] = (__bf16)acc;
    float ps = (c < 40) ? acc * att_src2[c] : 0.f;
    float pd = (c < 40) ? acc * att_dst2[c] : 0.f;
#pragma unroll
    for (int m = 32; m >= 1; m >>= 1) {
        ps += __shfl_xor(ps, m);
        pd += __shfl_xor(pd, m);
    }
    if (lane == 0) { a_src2[node] = ps; a_dst2[node] = pd; }
}

// ---------------------------------------------------------------------------
// agg2 + bias + log_softmax: wave per dst node, single pass, bf16 H2 gathers.
// ---------------------------------------------------------------------------
__global__ __launch_bounds__(256) void agg2(const int* __restrict__ off,
                                            const int* __restrict__ slot,
                                            const __bf16* __restrict__ H2b,
                                            const float* __restrict__ a_src2,
                                            const float* __restrict__ a_d2,
                                            const float* __restrict__ b2,
                                            float* __restrict__ out) {
    int wid = threadIdx.x >> 6, lane = threadIdx.x & 63;
    int d = blockIdx.x * 4 + wid;  // grid exact
    int beg = off[d], end = off[d + 1];
    float adst = a_d2[d];
    int c = lane;
    int cc = (c < 40) ? c : 0;
    float acc = 0.f, den = 0.f;
    for (int i = beg; i < end; i += 64) {
        int j = i + lane;
        int jj = (j < end) ? j : (end - 1);
        int s = slot[jj];
        float e = a_src2[s] + adst;
        e = (e >= 0.f) ? e : NEG_SLOPE * e;
        float w = (j < end) ? __expf(e) : 0.f;
#pragma unroll
        for (int qb = 0; qb < 8; ++qb) {
            if (i + (qb << 3) >= end) break;  // uniform branch
#pragma unroll
            for (int qq = 0; qq < 8; ++qq) {
                int q = (qb << 3) + qq;
                int sq = __shfl(s, q);
                float wq = __shfl(w, q);
                acc += wq * (float)H2b[(size_t)sq * 40 + cc];
                den += wq;
            }
        }
    }
    float v = acc / (den + 1e-16f) + b2[cc];
    float vm = (c < 40) ? v : -3.0e38f;
#pragma unroll
    for (int m = 32; m >= 1; m >>= 1) vm = fmaxf(vm, __shfl_xor(vm, m));
    float se = (c < 40) ? __expf(v - vm) : 0.f;
#pragma unroll
    for (int m = 32; m >= 1; m >>= 1) se += __shfl_xor(se, m);
    float res = v - vm - __logf(se);
    if (c < 40) out[(size_t)d * 40 + c] = res;
}

// ---------------------------------------------------------------------------
extern "C" void kernel_launch(void* const* d_in, const int* in_sizes, int n_in,
                              void* d_out, int out_size, void* d_ws, size_t ws_size,
                              hipStream_t stream) {
    const float* x   = (const float*)d_in[0];
    const int*   ei  = (const int*)d_in[1];
    const float* W1  = (const float*)d_in[2];
    const float* as1 = (const float*)d_in[3];
    const float* ad1 = (const float*)d_in[4];
    const float* b1  = (const float*)d_in[5];
    const float* W2  = (const float*)d_in[6];
    const float* as2 = (const float*)d_in[7];
    const float* ad2 = (const float*)d_in[8];
    const float* b2  = (const float*)d_in[9];
    float* out = (float*)d_out;

    const int N = NNODES;
    const int E = in_sizes[1] / 2;
    const int total = E + N;

    // workspace carve-up
    char* ws = (char*)d_ws;
    size_t o = 0;
    auto alloc = [&](size_t bytes) -> void* {
        void* p = ws + o;
        o = (o + bytes + 255) & ~(size_t)255;
        return p;
    };
    int* bcnt  = (int*)alloc((size_t)NB * 4);
    int* bbase = (int*)alloc((size_t)NB * 4);
    int* bcur  = (int*)alloc((size_t)NB * 4);
    int* off   = (int*)alloc((size_t)(N + 1) * 4);
    int* slot  = (int*)alloc((size_t)total * 4);
    __bf16* W1b = (__bf16*)alloc((size_t)512 * 64 * 2);
    __bf16* H1b = (__bf16*)alloc((size_t)N * 64 * 2);
    float* a_s1 = (float*)alloc((size_t)N * 8 * 4);
    float* a_d1 = (float*)alloc((size_t)N * 8 * 4);
    float* H1R  = (float*)alloc((size_t)N * 64 * 4);
    __bf16* H2b = (__bf16*)alloc((size_t)N * 40 * 2);
    float* a_s2 = (float*)alloc((size_t)N * 4);
    float* a_d2 = (float*)alloc((size_t)N * 4);
    int* tmp = (int*)H1R;  // alias: tmp dead before agg1 writes H1R
    (void)ws_size; (void)n_in; (void)out_size;

    // CSR build (binned counting sort; shared by both layers)
    hipMemsetAsync(bcnt, 0, (size_t)NB * 4, stream);
    bucket_count<<<512, 256, 0, stream>>>(ei, E, N, bcnt);
    scan_buckets<<<1, 512, 0, stream>>>(bcnt, bbase, bcur, off, N, total);
    bin_scatter<<<(total + CHUNK - 1) / CHUNK, 256, 0, stream>>>(ei, E, N, bcur, tmp);
    csr_finalize<<<NB, 256, 0, stream>>>(bbase, bcnt, tmp, N, off, slot);

    // Layer 1
    prep_w1<<<(512 * 64 + 255) / 256, 256, 0, stream>>>(W1, W1b);
    gemm1_mfma<<<(N + 63) / 64, 256, 0, stream>>>(x, W1b, H1b, N);
    att1_kernel<<<(N * 8 + 255) / 256, 256, 0, stream>>>(H1b, as1, ad1, a_s1, a_d1, N);
    agg1<<<N / 4, 256, 0, stream>>>(off, slot, H1b, a_s1, a_d1, b1, H1R);

    // Layer 2
    gemm2_att2<<<N / 4, 256, 0, stream>>>(H1R, W2, as2, ad2, H2b, a_s2, a_d2);
    agg2<<<N / 4, 256, 0, stream>>>(off, slot, H2b, a_s2, a_d2, b2, out);
}

// Round 6
// 363.250 us; speedup vs baseline: 2.3932x; 1.1143x over previous
//
#include <hip/hip_runtime.h>
#include <math.h>

#define NNODES 50000
#define NEG_SLOPE 0.2f
#define NB 391       // ceil(50000/128) buckets
#define BW 128       // nodes per bucket
#define CHUNK 8192   // edges per block in bin_scatter
#define CAP 8128     // arena slots per bucket in tmp (mean 4224, sigma ~64)

typedef __bf16 bf16x8 __attribute__((ext_vector_type(8)));
typedef float f32x4 __attribute__((ext_vector_type(4)));

// ---------------------------------------------------------------------------
// CSR build: fixed-stride bucket arena for tmp; slot compacted via gcur.
// bcur[NB] doubles as the global compaction cursor (gcur).
// ---------------------------------------------------------------------------
__global__ void init_bcur(int* bcur) {
    int i = blockIdx.x * 256 + threadIdx.x;
    if (i < NB) bcur[i] = i * CAP;
    if (i == NB) bcur[NB] = 0;  // gcur
}

// Per-block: LDS bucket histogram -> one reservation atomic per bucket ->
// write packed (dst&127)<<16|src into block-private contiguous runs of tmp.
__global__ __launch_bounds__(256) void bin_scatter(const int* __restrict__ ei,
                                                   int E, int N, int* bcur,
                                                   int* __restrict__ tmp) {
    __shared__ int lcnt[NB];
    __shared__ int lbase[NB];
    int tid = threadIdx.x;
    int base0 = blockIdx.x * CHUNK;
    int lim = min(base0 + CHUNK, E + N);
    for (int i = tid; i < NB; i += 256) lcnt[i] = 0;
    __syncthreads();
    for (int e = base0 + tid; e < lim; e += 256) {
        int d = (e < E) ? ei[E + e] : e - E;  // row 1 = dst; tail = self-loops
        atomicAdd(&lcnt[d >> 7], 1);
    }
    __syncthreads();
    for (int b = tid; b < NB; b += 256) {
        int c = lcnt[b];
        lbase[b] = c ? atomicAdd(&bcur[b], c) : 0;
    }
    __syncthreads();
    for (int i = tid; i < NB; i += 256) lcnt[i] = 0;
    __syncthreads();
    for (int e = base0 + tid; e < lim; e += 256) {
        int s, d;
        if (e < E) { s = ei[e]; d = ei[E + e]; }
        else       { s = d = e - E; }
        int b = d >> 7;
        int p = atomicAdd(&lcnt[b], 1);
        tmp[lbase[b] + p] = ((d & 127) << 16) | s;  // src < 50000 < 2^16
    }
}

// One block per bucket: per-node LDS count + scan; block reserves m compact
// slots from gcur; writes off/off_end and scatters slot within [cbase,cbase+m).
__global__ __launch_bounds__(256) void csr_finalize(int* __restrict__ bcur,
                                                    const int* __restrict__ tmp,
                                                    int N, int* __restrict__ off,
                                                    int* __restrict__ off_end,
                                                    int* __restrict__ slot) {
    __shared__ int cnt[BW];
    __shared__ int cur[BW];
    __shared__ int cbase_s;
    int b = blockIdx.x, tid = threadIdx.x;
    int base = b * CAP;
    int m = bcur[b] - base;
    if (tid < BW) cnt[tid] = 0;
    __syncthreads();
    for (int i = tid; i < m; i += 256)
        atomicAdd(&cnt[(tmp[base + i] >> 16) & 127], 1);
    __syncthreads();
    if (tid == 0) cbase_s = atomicAdd(&bcur[NB], m);  // compact reservation
    int myv = (tid < BW) ? cnt[tid] : 0;
    for (int o = 1; o < BW; o <<= 1) {
        int u = 0;
        if (tid >= o && tid < BW) u = cnt[tid - o];
        __syncthreads();
        if (tid < BW) cnt[tid] += u;
        __syncthreads();
    }
    if (tid < BW) {
        int ex = cbase_s + cnt[tid] - myv;  // exclusive, compact coords
        cur[tid] = ex;
        int g = b * BW + tid;
        if (g < N) { off[g] = ex; off_end[g] = ex + myv; }
    }
    __syncthreads();
    for (int i = tid; i < m; i += 256) {
        int v = tmp[base + i];
        int k = (v >> 16) & 127;
        int p = atomicAdd(&cur[k], 1);
        slot[p] = v & 0xFFFF;
    }
}

// ---------------------------------------------------------------------------
// prep_w1: W1[512,64] f32 -> bf16, panelized [k/8][n][k%8] for b-fragments.
// ---------------------------------------------------------------------------
__global__ void prep_w1(const float* __restrict__ W1, __bf16* __restrict__ W1b) {
    int i = blockIdx.x * 256 + threadIdx.x;  // over 512*64
    if (i >= 512 * 64) return;
    int k = i >> 6, n = i & 63;
    W1b[((size_t)(k >> 3) * 64 + n) * 8 + (k & 7)] = (__bf16)W1[i];
}

// ---------------------------------------------------------------------------
// gemm1_mfma: H1b[M,64](bf16) = bf16(X[M,512]) @ bf16(W1[512,64]).
// ---------------------------------------------------------------------------
__global__ __launch_bounds__(256) void gemm1_mfma(const float* __restrict__ X,
                                                  const __bf16* __restrict__ W1b,
                                                  __bf16* __restrict__ H1b, int M) {
    __shared__ __bf16 As[2048];  // [kq 0..3][m 0..63][8]
    __shared__ __bf16 Bs[2048];  // [kq 0..3][n 0..63][8]
    int tid = threadIdx.x, wid = tid >> 6, lane = tid & 63;
    int quad = lane >> 4, l15 = lane & 15;
    int m0 = blockIdx.x * 64;
    f32x4 acc[4] = {{0.f, 0.f, 0.f, 0.f}, {0.f, 0.f, 0.f, 0.f},
                    {0.f, 0.f, 0.f, 0.f}, {0.f, 0.f, 0.f, 0.f}};
    int mrow = tid >> 2;   // 0..63 (staging role)
    int kq_w = tid & 3;    // k-chunk (staging role)
    int xrow = min(m0 + mrow, M - 1);  // clamp: garbage rows never stored
    const float* xp = X + (size_t)xrow * 512 + kq_w * 8;
    for (int kb = 0; kb < 16; ++kb) {
        float4 xa = *(const float4*)(xp + kb * 32);
        float4 xb = *(const float4*)(xp + kb * 32 + 4);
        bf16x8 av;
        av[0] = (__bf16)xa.x; av[1] = (__bf16)xa.y;
        av[2] = (__bf16)xa.z; av[3] = (__bf16)xa.w;
        av[4] = (__bf16)xb.x; av[5] = (__bf16)xb.y;
        av[6] = (__bf16)xb.z; av[7] = (__bf16)xb.w;
        *(bf16x8*)(As + ((size_t)kq_w * 64 + mrow) * 8) = av;
        *(bf16x8*)(Bs + ((size_t)wid * 64 + lane) * 8) =
            *(const bf16x8*)(W1b + ((size_t)(kb * 4 + wid) * 64 + lane) * 8);
        __syncthreads();
        bf16x8 af = *(const bf16x8*)(As + ((size_t)quad * 64 + 16 * wid + l15) * 8);
#pragma unroll
        for (int t = 0; t < 4; ++t) {
            bf16x8 bf = *(const bf16x8*)(Bs + ((size_t)quad * 64 + 16 * t + l15) * 8);
            acc[t] = __builtin_amdgcn_mfma_f32_16x16x32_bf16(af, bf, acc[t], 0, 0, 0);
        }
        __syncthreads();
    }
#pragma unroll
    for (int t = 0; t < 4; ++t) {
#pragma unroll
        for (int r = 0; r < 4; ++r) {
            int gm = m0 + 16 * wid + quad * 4 + r;
            if (gm < M) H1b[(size_t)gm * 64 + 16 * t + l15] = (__bf16)acc[t][r];
        }
    }
}

// ---------------------------------------------------------------------------
// att1: a_src1[n,h], a_dst1[n,h] from H1b[n, h*8+c] (bf16)
// ---------------------------------------------------------------------------
__global__ void att1_kernel(const __bf16* __restrict__ H1b,
                            const float* __restrict__ att_src,
                            const float* __restrict__ att_dst,
                            float* __restrict__ a_src, float* __restrict__ a_dst,
                            int N) {
    int idx = blockIdx.x * 256 + threadIdx.x;  // idx = n*8 + h
    if (idx >= N * 8) return;
    int h = idx & 7;
    bf16x8 hv = *(const bf16x8*)(H1b + (size_t)idx * 8);
    const float* sp = att_src + h * 8;
    const float* dp = att_dst + h * 8;
    float as = 0.f, ad = 0.f;
#pragma unroll
    for (int j = 0; j < 8; ++j) {
        float hf = (float)hv[j];
        as += hf * sp[j];
        ad += hf * dp[j];
    }
    a_src[idx] = as;
    a_dst[idx] = ad;
}

// ---------------------------------------------------------------------------
// agg1: wave per dst node, single pass. s-broadcast via readlane (SGPR base
// for the gather); w-broadcast stays __shfl (lane-dependent source index).
// den accumulated per-lane, reduced once at the end.
// ---------------------------------------------------------------------------
__global__ __launch_bounds__(256) void agg1(const int* __restrict__ off,
                                            const int* __restrict__ off_end,
                                            const int* __restrict__ slot,
                                            const __bf16* __restrict__ H1b,
                                            const float* __restrict__ a_src,
                                            const float* __restrict__ a_dst,
                                            const float* __restrict__ b1,
                                            float* __restrict__ H1R) {
    int wid = threadIdx.x >> 6, lane = threadIdx.x & 63;
    int d = blockIdx.x * 4 + wid;  // grid exact: 12500*4 = 50000
    int beg = off[d], end = off_end[d];
    int h = lane >> 3;   // acc-role head (feature index = lane)
    int eh = lane & 7;   // compute-role head
    int es = lane >> 3;  // compute-role edge sub-index
    float adst_c = a_dst[(size_t)d * 8 + eh];
    float acc = 0.f, den_l = 0.f;
    for (int i = beg; i < end; i += 8) {
        int j = i + es;
        int jj = (j < end) ? j : (end - 1);
        int s = slot[jj];
        float e = a_src[(size_t)s * 8 + eh] + adst_c;
        e = (e >= 0.f) ? e : NEG_SLOPE * e;
        float w = (j < end) ? __expf(e) : 0.f;
        den_l += w;
#pragma unroll
        for (int q = 0; q < 8; ++q) {
            int sq = __builtin_amdgcn_readlane(s, q << 3);
            float wq = __shfl(w, (q << 3) | h);
            acc += wq * (float)H1b[(size_t)sq * 64 + lane];
        }
    }
    // den_l at lane L holds partial for head L&7; reduce over es (bits 3..5)
    den_l += __shfl_xor(den_l, 8);
    den_l += __shfl_xor(den_l, 16);
    den_l += __shfl_xor(den_l, 32);
    float den = __shfl(den_l, h);  // head h lives at lane h (es=0)
    float v = acc / (den + 1e-16f) + b1[lane];
    H1R[(size_t)d * 64 + lane] = (v > 0.f) ? v : 0.f;
}

// ---------------------------------------------------------------------------
// GEMM2 + att2 fused: wave per node. H2b bf16 out.
// ---------------------------------------------------------------------------
__global__ __launch_bounds__(256) void gemm2_att2(const float* __restrict__ H1R,
                                                  const float* __restrict__ W2,
                                                  const float* __restrict__ att_src2,
                                                  const float* __restrict__ att_dst2,
                                                  __bf16* __restrict__ H2b,
                                                  float* __restrict__ a_src2,
                                                  float* __restrict__ a_dst2) {
    __shared__ float W2s[64 * 40];
    __shared__ float rows[4][64];
    int tid = threadIdx.x;
    int wid = tid >> 6, lane = tid & 63;
    for (int i = tid; i < 64 * 40; i += 256) W2s[i] = W2[i];
    int node = blockIdx.x * 4 + wid;  // grid exact
    rows[wid][lane] = H1R[(size_t)node * 64 + lane];
    __syncthreads();
    int c = lane;
    int cc = (c < 40) ? c : 0;
    float acc = 0.f;
#pragma unroll 8
    for (int k = 0; k < 64; ++k) acc += rows[wid][k] * W2s[k * 40 + cc];
    if (c < 40) H2b[(size_t)node * 40 + c] = (__bf16)acc;
    float ps = (c < 40) ? acc * att_src2[c] : 0.f;
    float pd = (c < 40) ? acc * att_dst2[c] : 0.f;
#pragma unroll
    for (int m = 32; m >= 1; m >>= 1) {
        ps += __shfl_xor(ps, m);
        pd += __shfl_xor(pd, m);
    }
    if (lane == 0) { a_src2[node] = ps; a_dst2[node] = pd; }
}

// ---------------------------------------------------------------------------
// agg2 + bias + log_softmax: wave per dst node, single pass, bf16 H2 gathers.
// Broadcasts via readlane (SGPR, no LDS pipe); den out of inner loop.
// ---------------------------------------------------------------------------
__global__ __launch_bounds__(256) void agg2(const int* __restrict__ off,
                                            const int* __restrict__ off_end,
                                            const int* __restrict__ slot,
                                            const __bf16* __restrict__ H2b,
                                            const float* __restrict__ a_src2,
                                            const float* __restrict__ a_d2,
                                            const float* __restrict__ b2,
                                            float* __restrict__ out) {
    int wid = threadIdx.x >> 6, lane = threadIdx.x & 63;
    int d = blockIdx.x * 4 + wid;  // grid exact
    int beg = off[d], end = off_end[d];
    float adst = a_d2[d];
    int c = lane;
    int cc = (c < 40) ? c : 0;
    float acc = 0.f, den = 0.f;
    for (int i = beg; i < end; i += 64) {
        int j = i + lane;
        int jj = (j < end) ? j : (end - 1);
        int s = slot[jj];
        float e = a_src2[s] + adst;
        e = (e >= 0.f) ? e : NEG_SLOPE * e;
        float w = (j < end) ? __expf(e) : 0.f;
        den += w;  // per-lane; reduced after the loop
#pragma unroll
        for (int qb = 0; qb < 8; ++qb) {
            if (i + (qb << 3) >= end) break;  // uniform branch
#pragma unroll
            for (int qq = 0; qq < 8; ++qq) {
                int q = (qb << 3) + qq;
                int sq = __builtin_amdgcn_readlane(s, q);
                float wq = __uint_as_float(
                    __builtin_amdgcn_readlane((int)__float_as_uint(w), q));
                acc += wq * (float)H2b[(size_t)sq * 40 + cc];
            }
        }
    }
#pragma unroll
    for (int m = 32; m >= 1; m >>= 1) den += __shfl_xor(den, m);
    float v = acc / (den + 1e-16f) + b2[cc];
    float vm = (c < 40) ? v : -3.0e38f;
#pragma unroll
    for (int m = 32; m >= 1; m >>= 1) vm = fmaxf(vm, __shfl_xor(vm, m));
    float se = (c < 40) ? __expf(v - vm) : 0.f;
#pragma unroll
    for (int m = 32; m >= 1; m >>= 1) se += __shfl_xor(se, m);
    float res = v - vm - __logf(se);
    if (c < 40) out[(size_t)d * 40 + c] = res;
}

// ---------------------------------------------------------------------------
extern "C" void kernel_launch(void* const* d_in, const int* in_sizes, int n_in,
                              void* d_out, int out_size, void* d_ws, size_t ws_size,
                              hipStream_t stream) {
    const float* x   = (const float*)d_in[0];
    const int*   ei  = (const int*)d_in[1];
    const float* W1  = (const float*)d_in[2];
    const float* as1 = (const float*)d_in[3];
    const float* ad1 = (const float*)d_in[4];
    const float* b1  = (const float*)d_in[5];
    const float* W2  = (const float*)d_in[6];
    const float* as2 = (const float*)d_in[7];
    const float* ad2 = (const float*)d_in[8];
    const float* b2  = (const float*)d_in[9];
    float* out = (float*)d_out;

    const int N = NNODES;
    const int E = in_sizes[1] / 2;
    const int total = E + N;

    // workspace carve-up
    char* ws = (char*)d_ws;
    size_t o = 0;
    auto alloc = [&](size_t bytes) -> void* {
        void* p = ws + o;
        o = (o + bytes + 255) & ~(size_t)255;
        return p;
    };
    int* bcur    = (int*)alloc((size_t)(NB + 1) * 4);  // +1: gcur at [NB]
    int* off     = (int*)alloc((size_t)N * 4);
    int* off_end = (int*)alloc((size_t)N * 4);
    int* slot    = (int*)alloc((size_t)total * 4);
    __bf16* W1b = (__bf16*)alloc((size_t)512 * 64 * 2);
    __bf16* H1b = (__bf16*)alloc((size_t)N * 64 * 2);
    float* a_s1 = (float*)alloc((size_t)N * 8 * 4);
    float* a_d1 = (float*)alloc((size_t)N * 8 * 4);
    float* H1R  = (float*)alloc((size_t)N * 64 * 4);
    __bf16* H2b = (__bf16*)alloc((size_t)N * 40 * 2);
    float* a_s2 = (float*)alloc((size_t)N * 4);
    float* a_d2 = (float*)alloc((size_t)N * 4);
    int* tmp = (int*)H1R;  // alias: NB*CAP = 3,178,048 ints <= N*64 floats; dead before agg1
    (void)ws_size; (void)n_in; (void)out_size;

    // CSR build (arena tmp + compacted slot; shared by both layers)
    init_bcur<<<(NB + 256) / 256, 256, 0, stream>>>(bcur);
    bin_scatter<<<(total + CHUNK - 1) / CHUNK, 256, 0, stream>>>(ei, E, N, bcur, tmp);
    csr_finalize<<<NB, 256, 0, stream>>>(bcur, tmp, N, off, off_end, slot);

    // Layer 1
    prep_w1<<<(512 * 64 + 255) / 256, 256, 0, stream>>>(W1, W1b);
    gemm1_mfma<<<(N + 63) / 64, 256, 0, stream>>>(x, W1b, H1b, N);
    att1_kernel<<<(N * 8 + 255) / 256, 256, 0, stream>>>(H1b, as1, ad1, a_s1, a_d1, N);
    agg1<<<N / 4, 256, 0, stream>>>(off, off_end, slot, H1b, a_s1, a_d1, b1, H1R);

    // Layer 2
    gemm2_att2<<<N / 4, 256, 0, stream>>>(H1R, W2, as2, ad2, H2b, a_s2, a_d2);
    agg2<<<N / 4, 256, 0, stream>>>(off, off_end, slot, H2b, a_s2, a_d2, b2, out);
}